// Round 6
// baseline (79.898 us; speedup 1.0000x reference)
//
#include <hip/hip_runtime.h>
#include <hip/hip_bf16.h>

typedef __attribute__((ext_vector_type(8))) short short8;
typedef __attribute__((ext_vector_type(4))) float f32x4;

#define KB 32            // K-chunks; block covers 8 hi = 2048 rules
#define HPB 8            // hi per block = 256/KB
#define ROWP 16          // padded floats per S row (aligned float4 reads)

__device__ __forceinline__ ushort f2bf(float f) {            // RNE via v_cvt
    __hip_bfloat16 h = __float2bfloat16(f);
    return *reinterpret_cast<ushort*>(&h);
}
__device__ __forceinline__ unsigned pk2(float a, float b) {
    return (unsigned)f2bf(a) | ((unsigned)f2bf(b) << 16);
}

// Block = (sample-tile of 16) x (k-chunk of 2048 rules). 4 waves, wave wv owns
// hi in [kb*8 + 2*wv, +2). A-frags live in LDS (VGPR<=64 -> 8 waves/SIMD).
__global__ __launch_bounds__(256, 8) void fz_main(
    const float* __restrict__ x, const float* __restrict__ center,
    const float* __restrict__ sigma, const float* __restrict__ W,
    const float* __restrict__ b, float* __restrict__ S /*[KB][N][ROWP]*/, int N)
{
    __shared__ float  mgs[16][33];      // memberships (padded: no bank conflict)
    __shared__ float  pr[16][20] __attribute__((aligned(16)));  // d6,d7 pair products
    __shared__ ushort plf[8][64][8] __attribute__((aligned(16))); // A-frags, 8 lo-steps
    __shared__ float  phs[16][HPB + 1]; // ph[sample][hi_local], fp32 exact (padded)
    __shared__ float  red[4][16][9];    // cross-wave fold

    const int t = threadIdx.x;
    const int tile = blockIdx.x >> 5;   // KB==32
    const int kb = blockIdx.x & (KB - 1);

    #pragma unroll
    for (int v = 0; v < 2; ++v) {       // 512 mg values, 2/thread
        int id = t + v * 256;
        int s = id >> 5, i = id & 31, m = i >> 2;
        float xv = x[(size_t)(tile * 16 + s) * 8 + m];
        float d = xv - center[i];
        float sg = sigma[i];
        mgs[s][i] = __expf(-d * d * 0.5f * sg * sg);
    }
    __syncthreads();
    {   // pair table pr[s][4*d6+d7]; ph values for the block's 8 hi
        int s = t >> 4, a = t & 15;
        pr[s][a] = mgs[s][24 + (a >> 2)] * mgs[s][28 + (a & 3)];
        if (a < HPB) {
            int hi = kb * HPB + a;
            phs[s][a] = mgs[s][hi >> 6] * mgs[s][4 + ((hi >> 4) & 3)]
                      * mgs[s][8 + ((hi >> 2) & 3)] * mgs[s][12 + (hi & 3)];
        }
    }
    __syncthreads();
    {   // A-frags: thread t builds 2 octets (16 ushorts, 2x ds_write_b128)
        const int ls = t >> 5;                       // lo-step, fixed per thread
        #pragma unroll
        for (int oct = 0; oct < 2; ++oct) {
            const int lane_e = (2 * t + oct) & 63;
            const int s = lane_e & 15;
            const int hi3 = lane_e >> 4;
            const int L0 = ls * 32 + hi3 * 8;        // lo = L0 + j, j = 0..7
            const float pqv = mgs[s][16 + (L0 >> 6)] * mgs[s][20 + ((L0 >> 4) & 3)];
            const int b7 = L0 & 8;
            const float4 r0 = *reinterpret_cast<const float4*>(&pr[s][b7]);
            const float4 r1 = *reinterpret_cast<const float4*>(&pr[s][b7 + 4]);
            unsigned Pk[4] = { pk2(pqv * r0.x, pqv * r0.y), pk2(pqv * r0.z, pqv * r0.w),
                               pk2(pqv * r1.x, pqv * r1.y), pk2(pqv * r1.z, pqv * r1.w) };
            *reinterpret_cast<short8*>(&plf[ls][lane_e][0]) =
                *reinterpret_cast<short8*>(&Pk[0]);
        }
    }
    __syncthreads();

    const int wv = t >> 6, lane = t & 63;
    const int c = lane & 15, kb4 = lane >> 4;

    // per-lane B source: W column c (stride 8) for c<8, b (stride 1) for c==8;
    // lanes c>8 load b harmlessly, zeroed at pack via mask (no exec divergence)
    const float* src = (c < 8) ? (W + c) : b;
    const int stride = (c < 8) ? 8 : 1;
    const unsigned lmask = (c <= 8) ? 0xFFFFFFFFu : 0u;

    const int hi_base = kb * HPB + wv * 2;
    const float* p = src + (size_t)(hi_base * 256 + kb4 * 8) * stride;
    const ptrdiff_t s32 = (ptrdiff_t)32 * stride;

    float bufA[8], bufB[8];
    #pragma unroll
    for (int j = 0; j < 8; ++j) bufA[j] = p[j * stride];     // preload step 0

    f32x4 master = {0.f, 0.f, 0.f, 0.f};
    f32x4 d = {0.f, 0.f, 0.f, 0.f};
    #pragma unroll
    for (int step = 0; step < 16; ++step) {          // rows contiguous: +32/step
        const float* pn = p + s32;
        float* nxt = (step & 1) ? bufA : bufB;
        if (step < 15) {
            #pragma unroll
            for (int j = 0; j < 8; ++j) nxt[j] = pn[j * stride];
        }
        const float* cu = (step & 1) ? bufB : bufA;
        unsigned Bp[4] = { pk2(cu[0], cu[1]) & lmask, pk2(cu[2], cu[3]) & lmask,
                           pk2(cu[4], cu[5]) & lmask, pk2(cu[6], cu[7]) & lmask };
        short8 B = *reinterpret_cast<short8*>(&Bp[0]);
        short8 A = *reinterpret_cast<const short8*>(&plf[step & 7][lane][0]);
        d = __builtin_amdgcn_mfma_f32_16x16x32_bf16(A, B, d, 0, 0, 0);
        if ((step & 7) == 7) {
            const int hil = step >> 3;               // fold ph, reset d
            #pragma unroll
            for (int r = 0; r < 4; ++r)
                master[r] += phs[kb4 * 4 + r][wv * 2 + hil] * d[r];
            d = (f32x4){0.f, 0.f, 0.f, 0.f};
        }
        p = pn;
    }

    // fold the 4 waves (disjoint hi) in LDS, one compact store per block
    if (c < 9) {
        #pragma unroll
        for (int r = 0; r < 4; ++r)
            red[wv][kb4 * 4 + r][c] = master[r];
    }
    __syncthreads();
    if (t < 144) {
        int s = t / 9, cc = t % 9;
        float v = red[0][s][cc] + red[1][s][cc] + red[2][s][cc] + red[3][s][cc];
        S[((size_t)kb * N + tile * 16 + s) * ROWP + cc] = v;
    }
}

__global__ __launch_bounds__(64) void fz_final(
    const float* __restrict__ x, const float* __restrict__ center,
    const float* __restrict__ sigma, const float* __restrict__ S,
    float* __restrict__ out, int N)
{
    int n = blockIdx.x * 64 + threadIdx.x;
    if (n >= N) return;
    float xv[8];
    #pragma unroll
    for (int m = 0; m < 8; ++m) xv[m] = x[(size_t)n * 8 + m];
    float denom = 1.f;                  // computed first: exp overlaps S loads below
    #pragma unroll
    for (int m = 0; m < 8; ++m) {       // sum_r fg factorizes exactly (fp32)
        float ssum = 0.f;
        #pragma unroll
        for (int j = 0; j < 4; ++j) {
            float dd = xv[m] - center[m * 4 + j];
            float sg = sigma[m * 4 + j];
            ssum += __expf(-dd * dd * 0.5f * sg * sg);
        }
        denom *= ssum;
    }
    float sc[9];
    #pragma unroll
    for (int cc = 0; cc < 9; ++cc) sc[cc] = 0.f;
    #pragma unroll
    for (int ch = 0; ch < KB; ++ch) {
        const float* p = S + ((size_t)ch * N + n) * ROWP;   // 64B-aligned row
        const float4 a  = *reinterpret_cast<const float4*>(p);
        const float4 bq = *reinterpret_cast<const float4*>(p + 4);
        sc[0] += a.x;  sc[1] += a.y;  sc[2] += a.z;  sc[3] += a.w;
        sc[4] += bq.x; sc[5] += bq.y; sc[6] += bq.z; sc[7] += bq.w;
        sc[8] += p[8];
    }
    float num = sc[8];
    #pragma unroll
    for (int m = 0; m < 8; ++m) num += xv[m] * sc[m];
    out[n] = num / denom;
}

extern "C" void kernel_launch(void* const* d_in, const int* in_sizes, int n_in,
                              void* d_out, int out_size, void* d_ws, size_t ws_size,
                              hipStream_t stream)
{
    const float* x      = (const float*)d_in[0];
    const float* center = (const float*)d_in[1];
    const float* sigma  = (const float*)d_in[2];
    const float* W      = (const float*)d_in[3];
    const float* b      = (const float*)d_in[4];
    float* out = (float*)d_out;
    const int N = in_sizes[0] / 8;          // 1024

    float* S = (float*)d_ws;                // KB*N*ROWP floats = 2 MB

    fz_main<<<(N / 16) * KB, 256, 0, stream>>>(x, center, sigma, W, b, S, N);
    fz_final<<<(N + 63) / 64, 64, 0, stream>>>(x, center, sigma, S, out, N);
}

// Round 7
// 77.848 us; speedup vs baseline: 1.0263x; 1.0263x over previous
//
#include <hip/hip_runtime.h>
#include <hip/hip_bf16.h>

typedef __attribute__((ext_vector_type(8))) short short8;
typedef __attribute__((ext_vector_type(4))) float f32x4;

#define KB 16            // K-chunks; block covers 16 hi = 4096 rules

__device__ __forceinline__ ushort f2bf(float f) {            // RNE via v_cvt
    __hip_bfloat16 h = __float2bfloat16(f);
    return *reinterpret_cast<ushort*>(&h);
}
__device__ __forceinline__ unsigned pk2(float a, float b) {
    return (unsigned)f2bf(a) | ((unsigned)f2bf(b) << 16);
}

// Block = (sample-tile of 16) x (k-chunk of 4096 rules). 4 waves, wave wv owns
// hi in [kb*16 + 4*wv, +4). Fully fused: block atomically adds its chunk's
// contribution (num_chunk / denom) directly into out (out pre-zeroed).
__global__ __launch_bounds__(256) void fz_main(
    const float* __restrict__ x, const float* __restrict__ center,
    const float* __restrict__ sigma, const float* __restrict__ W,
    const float* __restrict__ b, float* __restrict__ out, int N)
{
    __shared__ float  xs[16][9];        // x rows (pad 9: conflict-free)
    __shared__ float  mgs[16][33];      // memberships (padded rows)
    __shared__ float  pr[16][20] __attribute__((aligned(16)));  // d6,d7 pair products
    __shared__ ushort plf[8][64][8] __attribute__((aligned(16))); // A-frags, 8 lo-steps
    __shared__ float  phs[16][17];      // ph[sample][hi_local], fp32 exact (padded)
    __shared__ float  red[4][16][9];    // cross-wave fold

    const int t = threadIdx.x;
    const int tile = blockIdx.x >> 4;   // KB==16
    const int kb = blockIdx.x & (KB - 1);

    if (t < 128) {                      // stage x rows once
        int s = t >> 3, m = t & 7;
        xs[s][m] = x[(size_t)(tile * 16 + s) * 8 + m];
    }
    __syncthreads();
    #pragma unroll
    for (int v = 0; v < 2; ++v) {       // 512 mg values, 2/thread
        int id = t + v * 256;
        int s = id >> 5, i = id & 31, m = i >> 2;
        float d = xs[s][m] - center[i];
        float sg = sigma[i];
        mgs[s][i] = __expf(-d * d * 0.5f * sg * sg);
    }
    __syncthreads();
    {   // pair table pr[s][4*d6+d7] and ph values, 1 entry each per thread
        int s = t >> 4, a = t & 15;
        pr[s][a] = mgs[s][24 + (a >> 2)] * mgs[s][28 + (a & 3)];
        int hi = kb * KB + a;
        phs[s][a] = mgs[s][hi >> 6] * mgs[s][4 + ((hi >> 4) & 3)]
                  * mgs[s][8 + ((hi >> 2) & 3)] * mgs[s][12 + (hi & 3)];
    }
    __syncthreads();
    {   // A-frags: thread t builds 2 octets (16 ushorts, 2x ds_write_b128)
        const int ls = t >> 5;                       // lo-step, fixed per thread
        #pragma unroll
        for (int oct = 0; oct < 2; ++oct) {
            const int lane_e = (2 * t + oct) & 63;
            const int s = lane_e & 15;
            const int hi3 = lane_e >> 4;
            const int L0 = ls * 32 + hi3 * 8;        // lo = L0 + j, j = 0..7
            const float pqv = mgs[s][16 + (L0 >> 6)] * mgs[s][20 + ((L0 >> 4) & 3)];
            const int b7 = L0 & 8;
            const float4 r0 = *reinterpret_cast<const float4*>(&pr[s][b7]);
            const float4 r1 = *reinterpret_cast<const float4*>(&pr[s][b7 + 4]);
            unsigned Pk[4] = { pk2(pqv * r0.x, pqv * r0.y), pk2(pqv * r0.z, pqv * r0.w),
                               pk2(pqv * r1.x, pqv * r1.y), pk2(pqv * r1.z, pqv * r1.w) };
            *reinterpret_cast<short8*>(&plf[ls][lane_e][0]) =
                *reinterpret_cast<short8*>(&Pk[0]);
        }
    }
    __syncthreads();

    const int wv = t >> 6, lane = t & 63;
    const int c = lane & 15, kb4 = lane >> 4;
    short8 A[8];
    #pragma unroll
    for (int ls = 0; ls < 8; ++ls)      // wave's 8 A-frags, reused across all hi
        A[ls] = *reinterpret_cast<const short8*>(&plf[ls][lane][0]);

    // per-lane B source: W column c (stride 8) for c<8, b (stride 1) for c==8;
    // lanes c>8 load b harmlessly, zeroed at pack via mask (no exec divergence)
    const float* src = (c < 8) ? (W + c) : b;
    const int stride = (c < 8) ? 8 : 1;
    const unsigned lmask = (c <= 8) ? 0xFFFFFFFFu : 0u;

    const int hi_base = kb * KB + wv * 4;
    const float* p = src + (size_t)(hi_base * 256 + kb4 * 8) * stride;
    const ptrdiff_t s32 = (ptrdiff_t)32 * stride;

    float bufA[8], bufB[8];
    #pragma unroll
    for (int j = 0; j < 8; ++j) bufA[j] = p[j * stride];     // preload step 0

    f32x4 master = {0.f, 0.f, 0.f, 0.f};
    f32x4 d = {0.f, 0.f, 0.f, 0.f};
    #pragma unroll
    for (int step = 0; step < 32; ++step) {          // rows contiguous: +32/step
        const float* pn = p + s32;
        float* nxt = (step & 1) ? bufA : bufB;
        if (step < 31) {
            #pragma unroll
            for (int j = 0; j < 8; ++j) nxt[j] = pn[j * stride];
        }
        const float* cu = (step & 1) ? bufB : bufA;
        unsigned Bp[4] = { pk2(cu[0], cu[1]) & lmask, pk2(cu[2], cu[3]) & lmask,
                           pk2(cu[4], cu[5]) & lmask, pk2(cu[6], cu[7]) & lmask };
        short8 B = *reinterpret_cast<short8*>(&Bp[0]);
        d = __builtin_amdgcn_mfma_f32_16x16x32_bf16(A[step & 7], B, d, 0, 0, 0);
        if ((step & 7) == 7) {
            const int hil = step >> 3;               // fold ph, reset d
            #pragma unroll
            for (int r = 0; r < 4; ++r)
                master[r] += phs[kb4 * 4 + r][wv * 4 + hil] * d[r];
            d = (f32x4){0.f, 0.f, 0.f, 0.f};
        }
        p = pn;
    }

    // fold the 4 waves (disjoint hi) in LDS
    if (c < 9) {
        #pragma unroll
        for (int r = 0; r < 4; ++r)
            red[wv][kb4 * 4 + r][c] = master[r];
    }
    __syncthreads();
    if (t < 144) {
        int s = t / 9, cc = t % 9;
        red[0][s][cc] += red[1][s][cc] + red[2][s][cc] + red[3][s][cc];
    }
    __syncthreads();
    if (t < 16) {                       // finish: denom from mgs (exact), fused add
        const int s = t;
        float denom = 1.f;
        #pragma unroll
        for (int m = 0; m < 8; ++m)
            denom *= (mgs[s][4 * m] + mgs[s][4 * m + 1] +
                      mgs[s][4 * m + 2] + mgs[s][4 * m + 3]);
        float num = red[0][s][8];
        #pragma unroll
        for (int m = 0; m < 8; ++m) num += xs[s][m] * red[0][s][m];
        atomicAdd(&out[tile * 16 + s], num / denom);
    }
}

extern "C" void kernel_launch(void* const* d_in, const int* in_sizes, int n_in,
                              void* d_out, int out_size, void* d_ws, size_t ws_size,
                              hipStream_t stream)
{
    const float* x      = (const float*)d_in[0];
    const float* center = (const float*)d_in[1];
    const float* sigma  = (const float*)d_in[2];
    const float* W      = (const float*)d_in[3];
    const float* b      = (const float*)d_in[4];
    float* out = (float*)d_out;
    const int N = in_sizes[0] / 8;          // 1024

    hipMemsetAsync(out, 0, (size_t)out_size * sizeof(float), stream);
    fz_main<<<(N / 16) * KB, 256, 0, stream>>>(x, center, sigma, W, b, out, N);
}

// Round 8
// 74.265 us; speedup vs baseline: 1.0759x; 1.0482x over previous
//
#include <hip/hip_runtime.h>
#include <hip/hip_bf16.h>

typedef __attribute__((ext_vector_type(8))) short short8;
typedef __attribute__((ext_vector_type(4))) float f32x4;

#define KB 16            // K-chunks; block covers 16 hi = 4096 rules

__device__ __forceinline__ ushort f2bf(float f) {            // RNE via v_cvt
    __hip_bfloat16 h = __float2bfloat16(f);
    return *reinterpret_cast<ushort*>(&h);
}
__device__ __forceinline__ unsigned pk2(float a, float b) {
    return (unsigned)f2bf(a) | ((unsigned)f2bf(b) << 16);
}

// Block = (sample-tile of 16) x (k-chunk of 4096 rules = 16 hi). All 4 waves
// share each hi (k-split: wave wv owns K-steps {2wv, 2wv+1}); Wb for the hi is
// staged cooperatively into LDS as bf16 in MFMA-fragment order (coalesced
// global dwordx4 loads, conflict-free ds_read_b128 consumption), double-
// buffered with one barrier per hi. Block atomically adds its chunk's
// contribution (num_chunk / denom) directly into out (out pre-zeroed).
__global__ __launch_bounds__(256) void fz_main(
    const float* __restrict__ x, const float* __restrict__ center,
    const float* __restrict__ sigma, const float* __restrict__ W,
    const float* __restrict__ b, float* __restrict__ out, int N)
{
    __shared__ float  xs[16][9];        // x rows (pad 9: conflict-free)
    __shared__ float  mgs[16][33];      // memberships (padded rows)
    __shared__ float  pr[16][20] __attribute__((aligned(16)));  // d6,d7 pair products
    __shared__ ushort plf[8][64][8] __attribute__((aligned(16))); // A-frags, 8 lo-steps
    __shared__ float  phs[KB][20] __attribute__((aligned(16)));   // ph[hi][sample] (transposed)
    __shared__ float  red[4][16][9];    // cross-wave fold
    __shared__ ushort wstg[2][32][16][8] __attribute__((aligned(16)));
    // wstg[buf][rowblk][col][row&7]: element (row,col) of the staged 256x16 Wb
    // chunk lives at [row>>3][col][row&7] -> lane (c,kb4) reads its K-octet as
    // one 16B ds_read_b128 at [step*4+kb4][c][0]; 16 consecutive c = 256B
    // contiguous per 16-lane group -> zero bank conflicts.

    const int t = threadIdx.x;
    const int tile = blockIdx.x >> 4;   // KB==16
    const int kb = blockIdx.x & (KB - 1);

    if (t < 128) {                      // stage x rows once
        int s = t >> 3, m = t & 7;
        xs[s][m] = x[(size_t)(tile * 16 + s) * 8 + m];
    }
    __syncthreads();
    #pragma unroll
    for (int v = 0; v < 2; ++v) {       // 512 mg values, 2/thread
        int id = t + v * 256;
        int s = id >> 5, i = id & 31, m = i >> 2;
        float d = xs[s][m] - center[i];
        float sg = sigma[i];
        mgs[s][i] = __expf(-d * d * 0.5f * sg * sg);
    }
    __syncthreads();
    {   // pair table pr[s][4*d6+d7]
        int s = t >> 4, a = t & 15;
        pr[s][a] = mgs[s][24 + (a >> 2)] * mgs[s][28 + (a & 3)];
    }
    {   // ph table, transposed [hi][s]: one value per thread
        int hil = t >> 4, s = t & 15;
        int hi = kb * KB + hil;
        phs[hil][s] = mgs[s][hi >> 6] * mgs[s][4 + ((hi >> 4) & 3)]
                    * mgs[s][8 + ((hi >> 2) & 3)] * mgs[s][12 + (hi & 3)];
    }
    __syncthreads();
    {   // A-frags: thread t builds 2 octets (16 ushorts, 2x ds_write_b128)
        const int ls = t >> 5;                       // lo-step, fixed per thread
        #pragma unroll
        for (int oct = 0; oct < 2; ++oct) {
            const int lane_e = (2 * t + oct) & 63;
            const int s = lane_e & 15;
            const int hi3 = lane_e >> 4;
            const int L0 = ls * 32 + hi3 * 8;        // lo = L0 + j, j = 0..7
            const float pqv = mgs[s][16 + (L0 >> 6)] * mgs[s][20 + ((L0 >> 4) & 3)];
            const int b7 = L0 & 8;
            const float4 r0 = *reinterpret_cast<const float4*>(&pr[s][b7]);
            const float4 r1 = *reinterpret_cast<const float4*>(&pr[s][b7 + 4]);
            unsigned Pk[4] = { pk2(pqv * r0.x, pqv * r0.y), pk2(pqv * r0.z, pqv * r0.w),
                               pk2(pqv * r1.x, pqv * r1.y), pk2(pqv * r1.z, pqv * r1.w) };
            *reinterpret_cast<short8*>(&plf[ls][lane_e][0]) =
                *reinterpret_cast<short8*>(&Pk[0]);
        }
    }

    const int wv = t >> 6, lane = t & 63;
    const int c = lane & 15, kb4 = lane >> 4;
    const int srow = t >> 1, shalf = (t & 1) * 4;    // staging row/half-col

    // ---- staging helpers (per-thread: 3 coalesced VMEM, 9 cvt, 9 ds_write) --
    auto stage_load = [&](int hil, float4& va, float4& vb, float& bv) {
        const float* wp = W + (size_t)(kb * KB + hil) * 2048;
        va = *reinterpret_cast<const float4*>(wp + t * 4);          // 4KB contig
        vb = *reinterpret_cast<const float4*>(wp + 1024 + t * 4);   // next 4KB
        bv = b[(kb * KB + hil) * 256 + t];                          // 1KB contig
    };
    auto stage_write = [&](int bf, const float4& va, const float4& vb, float bv) {
        ushort* p0 = &wstg[bf][srow >> 3][shalf][srow & 7];         // row srow
        p0[0] = f2bf(va.x); p0[8] = f2bf(va.y); p0[16] = f2bf(va.z); p0[24] = f2bf(va.w);
        ushort* p1 = &wstg[bf][16 + (srow >> 3)][shalf][srow & 7];  // row 128+srow
        p1[0] = f2bf(vb.x); p1[8] = f2bf(vb.y); p1[16] = f2bf(vb.z); p1[24] = f2bf(vb.w);
        wstg[bf][t >> 3][8][t & 7] = f2bf(bv);                      // b -> col 8
    };

    __syncthreads();                     // A-frags/ph ready
    short8 A0 = *reinterpret_cast<const short8*>(&plf[2 * wv][lane][0]);
    short8 A1 = *reinterpret_cast<const short8*>(&plf[2 * wv + 1][lane][0]);

    float4 va, vb2; float bv;
    stage_load(0, va, vb2, bv);
    stage_write(0, va, vb2, bv);
    __syncthreads();

    f32x4 master = {0.f, 0.f, 0.f, 0.f};
    #pragma unroll 2
    for (int hil = 0; hil < KB; ++hil) {
        const int bf = hil & 1;
        if (hil + 1 < KB) stage_load(hil + 1, va, vb2, bv);  // VMEM in flight
        f32x4 d = {0.f, 0.f, 0.f, 0.f};
        short8 B0 = *reinterpret_cast<const short8*>(&wstg[bf][(2 * wv) * 4 + kb4][c][0]);
        short8 B1 = *reinterpret_cast<const short8*>(&wstg[bf][(2 * wv + 1) * 4 + kb4][c][0]);
        d = __builtin_amdgcn_mfma_f32_16x16x32_bf16(A0, B0, d, 0, 0, 0);
        d = __builtin_amdgcn_mfma_f32_16x16x32_bf16(A1, B1, d, 0, 0, 0);
        const float4 phv = *reinterpret_cast<const float4*>(&phs[hil][kb4 * 4]);
        master[0] += phv.x * d[0]; master[1] += phv.y * d[1];
        master[2] += phv.z * d[2]; master[3] += phv.w * d[3];
        if (hil + 1 < KB) stage_write(bf ^ 1, va, vb2, bv);
        __syncthreads();                 // next buffer visible to all waves
    }

    // fold the 4 waves (disjoint k-slices) in LDS
    if (c < 9) {
        #pragma unroll
        for (int r = 0; r < 4; ++r)
            red[wv][kb4 * 4 + r][c] = master[r];
    }
    __syncthreads();
    if (t < 144) {
        int s = t / 9, cc = t % 9;
        red[0][s][cc] += red[1][s][cc] + red[2][s][cc] + red[3][s][cc];
    }
    __syncthreads();
    if (t < 16) {                       // finish: denom from mgs (exact), fused add
        const int s = t;
        float denom = 1.f;
        #pragma unroll
        for (int m = 0; m < 8; ++m)
            denom *= (mgs[s][4 * m] + mgs[s][4 * m + 1] +
                      mgs[s][4 * m + 2] + mgs[s][4 * m + 3]);
        float num = red[0][s][8];
        #pragma unroll
        for (int m = 0; m < 8; ++m) num += xs[s][m] * red[0][s][m];
        atomicAdd(&out[tile * 16 + s], num / denom);
    }
}

extern "C" void kernel_launch(void* const* d_in, const int* in_sizes, int n_in,
                              void* d_out, int out_size, void* d_ws, size_t ws_size,
                              hipStream_t stream)
{
    const float* x      = (const float*)d_in[0];
    const float* center = (const float*)d_in[1];
    const float* sigma  = (const float*)d_in[2];
    const float* W      = (const float*)d_in[3];
    const float* b      = (const float*)d_in[4];
    float* out = (float*)d_out;
    const int N = in_sizes[0] / 8;          // 1024

    hipMemsetAsync(out, 0, (size_t)out_size * sizeof(float), stream);
    fz_main<<<(N / 16) * KB, 256, 0, stream>>>(x, center, sigma, W, b, out, N);
}

// Round 9
// 71.003 us; speedup vs baseline: 1.1253x; 1.0459x over previous
//
#include <hip/hip_runtime.h>
#include <hip/hip_bf16.h>

typedef __attribute__((ext_vector_type(8))) short short8;
typedef __attribute__((ext_vector_type(4))) float f32x4;

#define KB 16            // K-chunks; block covers 16 hi = 4096 rules

__device__ __forceinline__ ushort f2bf(float f) {            // RNE via v_cvt
    __hip_bfloat16 h = __float2bfloat16(f);
    return *reinterpret_cast<ushort*>(&h);
}
__device__ __forceinline__ unsigned pk2(float a, float b) {
    return (unsigned)f2bf(a) | ((unsigned)f2bf(b) << 16);
}

// Block = (sample-tile of 16) x (k-chunk of 4096 rules = 16 hi).
// k-split: wave wv owns K-steps {2wv, 2wv+1} of every hi -> its B-rows are
// exactly rows 64wv..64wv+63 of each staged 256-row chunk. Each wave stages
// its own rows into a PRIVATE LDS region (lane l stages row 64wv+l: one
// 32B-contiguous W row + b), so the 16-iteration hot loop has ZERO barriers —
// within-wave LDS ordering + double buffering give correctness, and the four
// waves free-run to hide each other's VMEM latency. 4 barriers total.
__global__ __launch_bounds__(256) void fz_main(
    const float* __restrict__ x, const float* __restrict__ center,
    const float* __restrict__ sigma, const float* __restrict__ W,
    const float* __restrict__ b, float* __restrict__ out, int N)
{
    __shared__ float  mgs[16][33];      // memberships (padded rows)
    __shared__ float  pr[16][20]  __attribute__((aligned(16)));  // d6,d7 pair products
    __shared__ float  phs[KB][20] __attribute__((aligned(16)));  // ph[hi][sample]
    __shared__ float  red[4][16][9];    // cross-wave fold
    __shared__ ushort wstg[4][2][8][17][8] __attribute__((aligned(16)));
    // wstg[wv][buf][rb][col][r8]: element (row,col) of wave wv's 64-row slice
    // at [row>>3][col][row&7]. col dim padded to 17 -> rb stride 136 ushorts
    // (68 dwords == 4 mod 32): the 9 per-lane ds_write_b16 land on all 32
    // banks. Reads are 16B-aligned b128 at the LDS BW floor.

    const int t = threadIdx.x;
    const int tile = blockIdx.x >> 4;   // KB==16
    const int kb = blockIdx.x & (KB - 1);

    #pragma unroll
    for (int v = 0; v < 2; ++v) {       // 512 mg values, 2/thread, x from global
        int id = t + v * 256;
        int s = id >> 5, i = id & 31, m = i >> 2;
        float xv = x[(size_t)(tile * 16 + s) * 8 + m];
        float d = xv - center[i];
        float sg = sigma[i];
        mgs[s][i] = __expf(-d * d * 0.5f * sg * sg);
    }
    __syncthreads();
    {   // pair table pr[s][4*d6+d7], one entry per thread
        int s = t >> 4, a = t & 15;
        pr[s][a] = mgs[s][24 + (a >> 2)] * mgs[s][28 + (a & 3)];
    }
    {   // ph table, transposed [hi][s]: one value per thread (fp32 exact)
        int hil = t >> 4, s = t & 15;
        int hi = kb * KB + hil;
        phs[hil][s] = mgs[s][hi >> 6] * mgs[s][4 + ((hi >> 4) & 3)]
                    * mgs[s][8 + ((hi >> 2) & 3)] * mgs[s][12 + (hi & 3)];
    }
    __syncthreads();

    const int wv = t >> 6, lane = t & 63;
    const int c = lane & 15, kb4 = lane >> 4;

    // A-frags built per-wave in registers (no plf LDS stage, no barrier):
    // A[q] = pl(s = lane&15, k-octet of ls = 2wv+q), same k-map as B.
    short8 A[2];
    {
        const int s_a = lane & 15;
        #pragma unroll
        for (int q = 0; q < 2; ++q) {
            const int ls = 2 * wv + q;
            const int L0 = ls * 32 + kb4 * 8;        // lo = L0 + j, j = 0..7
            const float pq = mgs[s_a][16 + (L0 >> 6)] * mgs[s_a][20 + ((L0 >> 4) & 3)];
            const int b7 = L0 & 8;
            const float4 r0 = *reinterpret_cast<const float4*>(&pr[s_a][b7]);
            const float4 r1 = *reinterpret_cast<const float4*>(&pr[s_a][b7 + 4]);
            unsigned Pk[4] = { pk2(pq * r0.x, pq * r0.y), pk2(pq * r0.z, pq * r0.w),
                               pk2(pq * r1.x, pq * r1.y), pk2(pq * r1.z, pq * r1.w) };
            A[q] = *reinterpret_cast<short8*>(&Pk[0]);
        }
    }

    // wave-private staging: lane l owns global row (kb*16+hil)*256 + 64*wv + l
    const float*  wrow = W + ((size_t)kb * 4096 + 64 * wv + lane) * 8;
    const float*  brow = b + kb * 4096 + 64 * wv + lane;
    ushort* rg = &wstg[wv][0][0][0][0];          // 2 bufs x 1088 ushorts

    auto sload = [&](int hil, float4& wa, float4& wb, float& bv) {
        wa = *reinterpret_cast<const float4*>(wrow + hil * 2048);
        wb = *reinterpret_cast<const float4*>(wrow + hil * 2048 + 4);
        bv = brow[hil * 256];
    };
    auto swrite = [&](int buf, const float4& wa, const float4& wb, float bv) {
        ushort* p = rg + buf * 1088 + (lane >> 3) * 136 + (lane & 7);
        p[0]  = f2bf(wa.x); p[8]  = f2bf(wa.y); p[16] = f2bf(wa.z); p[24] = f2bf(wa.w);
        p[32] = f2bf(wb.x); p[40] = f2bf(wb.y); p[48] = f2bf(wb.z); p[56] = f2bf(wb.w);
        p[64] = f2bf(bv);                        // b -> col 8
    };

    float4 wa, wb2; float bv;
    sload(0, wa, wb2, bv);
    swrite(0, wa, wb2, bv);

    f32x4 master = {0.f, 0.f, 0.f, 0.f};
    #pragma unroll 4
    for (int hil = 0; hil < KB; ++hil) {         // ZERO barriers in this loop
        const int buf = hil & 1;
        if (hil + 1 < KB) sload(hil + 1, wa, wb2, bv);   // VMEM in flight
        // B: rb' = (ls&1)*4 + kb4; ls=2wv -> kb4, ls=2wv+1 -> 4+kb4
        const ushort* q = rg + buf * 1088 + kb4 * 136 + c * 8;
        short8 B0 = *reinterpret_cast<const short8*>(q);
        short8 B1 = *reinterpret_cast<const short8*>(q + 4 * 136);
        f32x4 d = {0.f, 0.f, 0.f, 0.f};
        d = __builtin_amdgcn_mfma_f32_16x16x32_bf16(A[0], B0, d, 0, 0, 0);
        d = __builtin_amdgcn_mfma_f32_16x16x32_bf16(A[1], B1, d, 0, 0, 0);
        const float4 phv = *reinterpret_cast<const float4*>(&phs[hil][kb4 * 4]);
        master[0] += phv.x * d[0]; master[1] += phv.y * d[1];
        master[2] += phv.z * d[2]; master[3] += phv.w * d[3];
        if (hil + 1 < KB) swrite(buf ^ 1, wa, wb2, bv);  // other buffer: no hazard
    }

    // fold the 4 waves (disjoint k-slices) in LDS
    if (c < 9) {
        #pragma unroll
        for (int r = 0; r < 4; ++r)
            red[wv][kb4 * 4 + r][c] = master[r];
    }
    __syncthreads();
    if (t < 144) {
        int s = t / 9, cc = t % 9;
        red[0][s][cc] += red[1][s][cc] + red[2][s][cc] + red[3][s][cc];
    }
    __syncthreads();
    if (t < 16) {                       // finish: denom from mgs (exact), fused add
        const int s = t;
        float denom = 1.f;
        #pragma unroll
        for (int m = 0; m < 8; ++m)
            denom *= (mgs[s][4 * m] + mgs[s][4 * m + 1] +
                      mgs[s][4 * m + 2] + mgs[s][4 * m + 3]);
        float num = red[0][s][8];
        #pragma unroll
        for (int m = 0; m < 8; ++m)
            num += x[(size_t)(tile * 16 + s) * 8 + m] * red[0][s][m];
        atomicAdd(&out[tile * 16 + s], num / denom);
    }
}

extern "C" void kernel_launch(void* const* d_in, const int* in_sizes, int n_in,
                              void* d_out, int out_size, void* d_ws, size_t ws_size,
                              hipStream_t stream)
{
    const float* x      = (const float*)d_in[0];
    const float* center = (const float*)d_in[1];
    const float* sigma  = (const float*)d_in[2];
    const float* W      = (const float*)d_in[3];
    const float* b      = (const float*)d_in[4];
    float* out = (float*)d_out;
    const int N = in_sizes[0] / 8;          // 1024

    hipMemsetAsync(out, 0, (size_t)out_size * sizeof(float), stream);
    fz_main<<<(N / 16) * KB, 256, 0, stream>>>(x, center, sigma, W, b, out, N);
}

// Round 11
// 69.912 us; speedup vs baseline: 1.1428x; 1.0156x over previous
//
#include <hip/hip_runtime.h>
#include <hip/hip_bf16.h>

typedef __attribute__((ext_vector_type(8))) short short8;
typedef __attribute__((ext_vector_type(4))) float f32x4;

#define KB 32            // K-chunks; block covers 8 hi = 2048 rules
#define HPB 8            // hi per block
#define SPT 32           // samples per block (2 MFMA sub-tiles of 16)

__device__ __forceinline__ ushort f2bf(float f) {            // RNE via v_cvt
    __hip_bfloat16 h = __float2bfloat16(f);
    return *reinterpret_cast<ushort*>(&h);
}
__device__ __forceinline__ unsigned pk2(float a, float b) {
    return (unsigned)f2bf(a) | ((unsigned)f2bf(b) << 16);
}

// Block = (sample-tile of 32) x (k-chunk of 2048 rules = 8 hi).
// k-split: wave wv owns K-steps {2wv, 2wv+1} of every hi -> its B-rows are
// local rows [64wv, 64wv+64) of each staged 256-row chunk, staged into a
// PRIVATE LDS region (lane l stages local row 64wv+l: one 32B-contiguous W
// row + b). Zero barriers in the hot loop; two 16-sample MFMA sub-tiles share
// each staged B fragment (halves L2 W-traffic vs 16-sample blocks). Block
// atomically adds its chunk's contribution into out (out pre-zeroed).
__global__ __launch_bounds__(256) void fz_main(
    const float* __restrict__ x, const float* __restrict__ center,
    const float* __restrict__ sigma, const float* __restrict__ W,
    const float* __restrict__ b, float* __restrict__ out, int N)
{
    __shared__ float  mgs[SPT][33];     // memberships (padded rows)
    __shared__ float  pr[SPT][20]  __attribute__((aligned(16))); // d6,d7 pair products
    __shared__ float  phs[HPB][36] __attribute__((aligned(16))); // ph[hi][sample]
    __shared__ float  red[4][SPT][9];   // cross-wave fold
    __shared__ ushort wstg[4][2][8][17][8] __attribute__((aligned(16)));
    // wstg[wv][buf][rb][col][r8]: element (local row,col) at [r>>3][c][r&7].
    // col dim padded to 17 -> rb stride 136 ushorts: per-lane ds_write_b16
    // spread over all 32 banks; reads are 16B-aligned ds_read_b128.

    const int t = threadIdx.x;
    const int tile = blockIdx.x >> 5;   // KB==32
    const int kb = blockIdx.x & (KB - 1);

    #pragma unroll
    for (int v = 0; v < 4; ++v) {       // 1024 mg values, 4/thread
        int id = t + v * 256;
        int s = id >> 5, i = id & 31, m = i >> 2;
        float xv = x[(size_t)(tile * SPT + s) * 8 + m];
        float d = xv - center[i];
        float sg = sigma[i];
        mgs[s][i] = __expf(-d * d * 0.5f * sg * sg);
    }
    __syncthreads();
    #pragma unroll
    for (int v = 0; v < 2; ++v) {       // pair table pr[s][4*d6+d7], 2/thread
        int s = (t >> 4) + v * 16, a = t & 15;
        pr[s][a] = mgs[s][24 + (a >> 2)] * mgs[s][28 + (a & 3)];
    }
    {   // ph table [hi][sample]: one value per thread (fp32 exact)
        int hil = t >> 5, s = t & 31;
        int hi = kb * HPB + hil;
        phs[hil][s] = mgs[s][hi >> 6] * mgs[s][4 + ((hi >> 4) & 3)]
                    * mgs[s][8 + ((hi >> 2) & 3)] * mgs[s][12 + (hi & 3)];
    }
    __syncthreads();

    const int wv = t >> 6, lane = t & 63;
    const int c = lane & 15, kb4 = lane >> 4;

    // A-frags in registers: A[st][q] = pl(sample st*16+(lane&15), k-step 2wv+q)
    short8 A[2][2];
    #pragma unroll
    for (int st = 0; st < 2; ++st) {
        const int s_a = st * 16 + (lane & 15);
        #pragma unroll
        for (int q = 0; q < 2; ++q) {
            const int ls = 2 * wv + q;
            const int L0 = ls * 32 + kb4 * 8;        // lo = L0 + j, j = 0..7
            const float pq = mgs[s_a][16 + (L0 >> 6)] * mgs[s_a][20 + ((L0 >> 4) & 3)];
            const int b7 = L0 & 8;
            const float4 r0 = *reinterpret_cast<const float4*>(&pr[s_a][b7]);
            const float4 r1 = *reinterpret_cast<const float4*>(&pr[s_a][b7 + 4]);
            unsigned Pk[4] = { pk2(pq * r0.x, pq * r0.y), pk2(pq * r0.z, pq * r0.w),
                               pk2(pq * r1.x, pq * r1.y), pk2(pq * r1.z, pq * r1.w) };
            A[st][q] = *reinterpret_cast<short8*>(&Pk[0]);
        }
    }

    // wave-private staging: lane l owns global rule row kb*2048 + hil*256 + 64wv + l
    const float* wrow = W + ((size_t)kb * 2048 + 64 * wv + lane) * 8;
    const float* brow = b + kb * 2048 + 64 * wv + lane;
    ushort* rg = &wstg[wv][0][0][0][0];          // 2 bufs x 1088 ushorts

    auto sload = [&](int hil, float4& wa, float4& wb, float& bv) {
        wa = *reinterpret_cast<const float4*>(wrow + hil * 2048);
        wb = *reinterpret_cast<const float4*>(wrow + hil * 2048 + 4);
        bv = brow[hil * 256];
    };
    auto swrite = [&](int buf, const float4& wa, const float4& wb, float bv) {
        ushort* p = rg + buf * 1088 + (lane >> 3) * 136 + (lane & 7);
        p[0]  = f2bf(wa.x); p[8]  = f2bf(wa.y); p[16] = f2bf(wa.z); p[24] = f2bf(wa.w);
        p[32] = f2bf(wb.x); p[40] = f2bf(wb.y); p[48] = f2bf(wb.z); p[56] = f2bf(wb.w);
        p[64] = f2bf(bv);                        // b -> col 8
    };

    float4 wa, wb2; float bv;
    sload(0, wa, wb2, bv);
    swrite(0, wa, wb2, bv);

    f32x4 master[2] = {{0.f, 0.f, 0.f, 0.f}, {0.f, 0.f, 0.f, 0.f}};
    #pragma unroll 4
    for (int hil = 0; hil < HPB; ++hil) {        // ZERO barriers in this loop
        const int buf = hil & 1;
        if (hil + 1 < HPB) sload(hil + 1, wa, wb2, bv);  // VMEM in flight
        const ushort* q = rg + buf * 1088 + kb4 * 136 + c * 8;
        short8 B0 = *reinterpret_cast<const short8*>(q);            // k-step 2wv
        short8 B1 = *reinterpret_cast<const short8*>(q + 4 * 136);  // k-step 2wv+1
        #pragma unroll
        for (int st = 0; st < 2; ++st) {
            f32x4 d = {0.f, 0.f, 0.f, 0.f};
            d = __builtin_amdgcn_mfma_f32_16x16x32_bf16(A[st][0], B0, d, 0, 0, 0);
            d = __builtin_amdgcn_mfma_f32_16x16x32_bf16(A[st][1], B1, d, 0, 0, 0);
            const float4 phv =
                *reinterpret_cast<const float4*>(&phs[hil][st * 16 + kb4 * 4]);
            master[st][0] += phv.x * d[0]; master[st][1] += phv.y * d[1];
            master[st][2] += phv.z * d[2]; master[st][3] += phv.w * d[3];
        }
        if (hil + 1 < HPB) swrite(buf ^ 1, wa, wb2, bv); // other buffer: no hazard
    }

    // fold the 4 waves (disjoint k-slices) in LDS
    if (c < 9) {
        #pragma unroll
        for (int st = 0; st < 2; ++st)
            #pragma unroll
            for (int r = 0; r < 4; ++r)
                red[wv][st * 16 + kb4 * 4 + r][c] = master[st][r];
    }
    __syncthreads();
    for (int id = t; id < SPT * 9; id += 256) {
        int s = id / 9, cc = id % 9;
        red[0][s][cc] += red[1][s][cc] + red[2][s][cc] + red[3][s][cc];
    }
    __syncthreads();
    if (t < SPT) {                      // finish: denom from mgs (exact), fused add
        const int s = t;
        float denom = 1.f;
        #pragma unroll
        for (int m = 0; m < 8; ++m)
            denom *= (mgs[s][4 * m] + mgs[s][4 * m + 1] +
                      mgs[s][4 * m + 2] + mgs[s][4 * m + 3]);
        float num = red[0][s][8];
        #pragma unroll
        for (int m = 0; m < 8; ++m)
            num += x[(size_t)(tile * SPT + s) * 8 + m] * red[0][s][m];
        atomicAdd(&out[tile * SPT + s], num / denom);
    }
}

extern "C" void kernel_launch(void* const* d_in, const int* in_sizes, int n_in,
                              void* d_out, int out_size, void* d_ws, size_t ws_size,
                              hipStream_t stream)
{
    const float* x      = (const float*)d_in[0];
    const float* center = (const float*)d_in[1];
    const float* sigma  = (const float*)d_in[2];
    const float* W      = (const float*)d_in[3];
    const float* b      = (const float*)d_in[4];
    float* out = (float*)d_out;
    const int N = in_sizes[0] / 8;          // 1024

    hipMemsetAsync(out, 0, (size_t)out_size * sizeof(float), stream);
    fz_main<<<(N / SPT) * KB, 256, 0, stream>>>(x, center, sigma, W, b, out, N);
}